// Round 5
// baseline (307.537 us; speedup 1.0000x reference)
//
#include <hip/hip_runtime.h>

#define NB 16
#define SQL 2048
#define SKL 2048
#define DH 64
#define NSPLIT 8
#define CHUNK 256          // keys per split = 4 tiles of 64
#define NQBLK (SQL / 128)

typedef __attribute__((ext_vector_type(8)))  short bf16x8;
typedef __attribute__((ext_vector_type(4)))  unsigned short u16x4;
typedef __attribute__((ext_vector_type(8)))  unsigned short u16x8;
typedef __attribute__((ext_vector_type(4)))  float f32x4;
typedef __attribute__((ext_vector_type(16))) float f32x16;

#define LOG2E 1.4426950408889634f
#define K1 (0.125f * LOG2E)   // 1/sqrt(64) folded into exp2 argument

__device__ __forceinline__ unsigned short f2bf(float f) {
    unsigned int u = __builtin_bit_cast(unsigned int, f);
    u += 0x7fffu + ((u >> 16) & 1u);
    return (unsigned short)(u >> 16);
}
__device__ __forceinline__ float bf2f(unsigned short h) {
    return __builtin_bit_cast(float, (unsigned int)h << 16);
}

// ---------------------------------------------------------------------------
// Prep: Q,K fp32->bf16 (blocks 0..2047), V fp32 -> V^T bf16 (blocks 2048..2559)
// ---------------------------------------------------------------------------
__global__ __launch_bounds__(256) void prep_kernel(
    const float* __restrict__ Q, const float* __restrict__ K,
    const float* __restrict__ V,
    unsigned short* __restrict__ Qb, unsigned short* __restrict__ Kb,
    unsigned short* __restrict__ Vt) {
    const int blk = blockIdx.x;
    if (blk < 2048) {
        const float* src = (blk < 1024) ? Q : K;
        unsigned short* dst = (blk < 1024) ? Qb : Kb;
        const size_t base = ((size_t)(blk & 1023) * 256 + threadIdx.x) * 8;
        float4 a = *(const float4*)(src + base);
        float4 b = *(const float4*)(src + base + 4);
        u16x8 o;
        o[0] = f2bf(a.x); o[1] = f2bf(a.y); o[2] = f2bf(a.z); o[3] = f2bf(a.w);
        o[4] = f2bf(b.x); o[5] = f2bf(b.y); o[6] = f2bf(b.z); o[7] = f2bf(b.w);
        *(u16x8*)(dst + base) = o;
    } else {
        const int t  = blk - 2048;
        const int b  = t >> 5;
        const int kb = (t & 31) << 6;
        __shared__ float tile[64][65];
        const int tid = threadIdx.x;
        {
            const int r  = tid >> 2;
            const int cg = (tid & 3) << 4;
            const float* vsrc = V + ((size_t)b * SKL + (kb + r)) * DH;
            #pragma unroll
            for (int i = 0; i < 4; ++i) {
                float4 x = *(const float4*)(vsrc + cg + i * 4);
                tile[r][cg + i*4 + 0] = x.x;
                tile[r][cg + i*4 + 1] = x.y;
                tile[r][cg + i*4 + 2] = x.z;
                tile[r][cg + i*4 + 3] = x.w;
            }
        }
        __syncthreads();
        {
            const int d  = tid >> 2;
            const int kg = (tid & 3) << 4;
            unsigned short* dst = Vt + ((size_t)b * DH + d) * SKL + kb + kg;
            u16x8 o0, o1;
            #pragma unroll
            for (int j = 0; j < 8; ++j) o0[j] = f2bf(tile[kg + j][d]);
            #pragma unroll
            for (int j = 0; j < 8; ++j) o1[j] = f2bf(tile[kg + 8 + j][d]);
            *(u16x8*)(dst)     = o0;
            *(u16x8*)(dst + 8) = o1;
        }
    }
}

// ---------------------------------------------------------------------------
// Flash attention with fused split-reduction (flash-decode style).
// Block = 4 waves, 128 q-rows (32/wave, q-col = lane&31), 32x32x16 MFMA,
// 16B-unit XOR-swizzled LDS. After partial write: __threadfence (device
// scope) + atomicAdd on per-(b,qblk) counter; last block combines.
// ns==1 batches write normalized output directly (no partial round-trip).
// ---------------------------------------------------------------------------
__global__ __launch_bounds__(256, 3) void attn_kernel(
    const unsigned short* __restrict__ Qb,
    const unsigned short* __restrict__ Kb,
    const unsigned short* __restrict__ Vt,
    const int* __restrict__ valid_lens,
    unsigned short* __restrict__ Opart,
    float2* __restrict__ MLpart,
    unsigned int* __restrict__ cnt,
    float* __restrict__ out) {
    const int qblk  = blockIdx.x;
    const int split = blockIdx.y;
    const int b     = blockIdx.z;

    const int valid  = valid_lens[b];
    const int kstart = split * CHUNK;
    if (kstart >= valid) return;                 // empty split
    const int kend    = (valid < kstart + CHUNK) ? valid : (kstart + CHUNK);
    const int ntiles  = (kend - kstart + 63) >> 6;
    const int nactive = (valid + CHUNK - 1) / CHUNK;   // 1..NSPLIT

    const int tid  = threadIdx.x;
    const int wave = tid >> 6;
    const int lane = tid & 63;
    const int l31  = lane & 31;
    const int h2   = lane >> 5;
    const int sw   = l31 & 7;                    // swizzle key

    __shared__ unsigned short Klds[64][64];      // [key][d], unit^=(key&7)
    __shared__ unsigned short Vlds[64][64];      // [d][key], unit^=(d&7)
    __shared__ unsigned short Plds[4][32][64];   // per-wave [q][key], unit^=(q&7)
    __shared__ int red_flag;

    // Q B-fragments: B[k=d][n=q], lane n=l31, k = ks*16 + h2*8 + j
    const int q0 = qblk * 128 + wave * 32;
    const unsigned short* qptr = Qb + ((size_t)b * SQL + q0 + l31) * DH + h2 * 8;
    bf16x8 qf[4];
    #pragma unroll
    for (int ks = 0; ks < 4; ++ks) qf[ks] = *(const bf16x8*)(qptr + ks * 16);

    const unsigned short* kbase = Kb + (size_t)b * SKL * DH;
    const unsigned short* vbase = Vt + (size_t)b * DH * SKL;

    f32x16 o[2];
    #pragma unroll
    for (int i = 0; i < 2; ++i)
        #pragma unroll
        for (int r = 0; r < 16; ++r) o[i][r] = 0.f;
    float mrow = -1e30f, lrow = 0.f;

    // staging registers (tile pipeline)
    u16x8 kreg[2], vreg[2];
    #pragma unroll
    for (int i = 0; i < 2; ++i) {
        const int c = i * 256 + tid, r = c >> 3, col = (c & 7) << 3;
        kreg[i] = *(const u16x8*)(kbase + (size_t)(kstart + r) * DH + col);
        vreg[i] = *(const u16x8*)(vbase + (size_t)r * SKL + kstart + col);
    }

    for (int kt = 0; kt < ntiles; ++kt) {
        const int kb = kstart + (kt << 6);
        __syncthreads();                         // prev tile's LDS reads done
        #pragma unroll
        for (int i = 0; i < 2; ++i) {
            const int c = i * 256 + tid, r = c >> 3;
            const int pc = ((c & 7) ^ (r & 7)) << 3;
            *(u16x8*)&Klds[r][pc] = kreg[i];
            *(u16x8*)&Vlds[r][pc] = vreg[i];
        }
        __syncthreads();
        if (kt + 1 < ntiles) {                   // preload next tile -> regs
            const int kn = kb + 64;
            #pragma unroll
            for (int i = 0; i < 2; ++i) {
                const int c = i * 256 + tid, r = c >> 3, col = (c & 7) << 3;
                kreg[i] = *(const u16x8*)(kbase + (size_t)(kn + r) * DH + col);
                vreg[i] = *(const u16x8*)(vbase + (size_t)r * SKL + kn + col);
            }
        }

        // ---- S^T = K . Q^T : 2 key-subtiles x 4 K-steps of 32x32x16 ----
        f32x16 s[2];
        #pragma unroll
        for (int t = 0; t < 2; ++t) {
            #pragma unroll
            for (int r = 0; r < 16; ++r) s[t][r] = 0.f;
            #pragma unroll
            for (int ks = 0; ks < 4; ++ks) {
                const bf16x8 kf = *(const bf16x8*)
                    &Klds[t * 32 + l31][((2 * ks + h2) ^ sw) << 3];
                s[t] = __builtin_amdgcn_mfma_f32_32x32x16_bf16(kf, qf[ks], s[t], 0, 0, 0);
            }
        }

        // ---- mask boundary tile; key(reg)=kb+t*32+(r&3)+8*(r>>2)+4*h2 ----
        if (kb + 64 > kend) {
            #pragma unroll
            for (int t = 0; t < 2; ++t)
                #pragma unroll
                for (int r = 0; r < 16; ++r)
                    if (kb + t * 32 + (r & 3) + 8 * (r >> 2) + 4 * h2 >= kend)
                        s[t][r] = -1e30f;
        }

        // ---- online softmax; q per-lane, rows split across lane^32 ----
        float tmax = -1e30f;
        #pragma unroll
        for (int t = 0; t < 2; ++t)
            #pragma unroll
            for (int r = 0; r < 16; ++r) tmax = fmaxf(tmax, s[t][r]);
        tmax = fmaxf(tmax, __shfl_xor(tmax, 32));

        const float mnew  = fmaxf(mrow, 0.125f * tmax);
        const float alpha = exp2f((mrow - mnew) * LOG2E);
        const float mk    = mnew * LOG2E;
        float rs = 0.f;
        #pragma unroll
        for (int t = 0; t < 2; ++t)
            #pragma unroll
            for (int r = 0; r < 16; ++r) {
                const float p = exp2f(fmaf(s[t][r], K1, -mk));
                s[t][r] = p;
                rs += p;
            }
        rs += __shfl_xor(rs, 32);
        lrow = lrow * alpha + rs;
        mrow = mnew;
        #pragma unroll
        for (int i = 0; i < 2; ++i)
            #pragma unroll
            for (int r = 0; r < 16; ++r) o[i][r] *= alpha;

        // ---- P -> LDS (bf16, swizzled): 8 writes of 4 contiguous keys ----
        #pragma unroll
        for (int t = 0; t < 2; ++t)
            #pragma unroll
            for (int g = 0; g < 4; ++g) {
                u16x4 pw;
                pw[0] = f2bf(s[t][g * 4 + 0]); pw[1] = f2bf(s[t][g * 4 + 1]);
                pw[2] = f2bf(s[t][g * 4 + 2]); pw[3] = f2bf(s[t][g * 4 + 3]);
                const int unit = (4 * t + g) ^ sw;
                *(u16x4*)&Plds[wave][l31][(unit << 3) + (h2 << 2)] = pw;
            }
        bf16x8 pf[4];
        #pragma unroll
        for (int ks = 0; ks < 4; ++ks)
            pf[ks] = *(const bf16x8*)&Plds[wave][l31][((2 * ks + h2) ^ sw) << 3];

        // ---- O^T += V^T . P^T : 2 d-subtiles x 4 K-steps ----
        #pragma unroll
        for (int dt = 0; dt < 2; ++dt)
            #pragma unroll
            for (int ks = 0; ks < 4; ++ks) {
                const bf16x8 vf = *(const bf16x8*)
                    &Vlds[dt * 32 + l31][((2 * ks + h2) ^ sw) << 3];
                o[dt] = __builtin_amdgcn_mfma_f32_32x32x16_bf16(vf, pf[ks], o[dt], 0, 0, 0);
            }
    }

    // ---- ns==1: write normalized output directly, done ----
    if (nactive == 1) {
        const float inv = 1.0f / lrow;
        float* op = out + ((size_t)b * SQL + q0 + l31) * DH;
        #pragma unroll
        for (int dt = 0; dt < 2; ++dt)
            #pragma unroll
            for (int g = 0; g < 4; ++g) {
                f32x4 ov;
                ov[0] = o[dt][g*4+0] * inv; ov[1] = o[dt][g*4+1] * inv;
                ov[2] = o[dt][g*4+2] * inv; ov[3] = o[dt][g*4+3] * inv;
                *(f32x4*)(op + dt * 32 + 8 * g + 4 * h2) = ov;
            }
        return;
    }

    // ---- partials: Opart[b][split][q][d] bf16; d = dt*32+8g+4h2+r ----
    unsigned short* op = Opart +
        (((size_t)b * NSPLIT + split) * SQL + q0 + l31) * DH;
    #pragma unroll
    for (int dt = 0; dt < 2; ++dt)
        #pragma unroll
        for (int g = 0; g < 4; ++g) {
            u16x4 ow;
            ow[0] = f2bf(o[dt][g * 4 + 0]); ow[1] = f2bf(o[dt][g * 4 + 1]);
            ow[2] = f2bf(o[dt][g * 4 + 2]); ow[3] = f2bf(o[dt][g * 4 + 3]);
            *(u16x4*)(op + dt * 32 + 8 * g + 4 * h2) = ow;
        }
    if (h2 == 0)
        MLpart[((size_t)b * NSPLIT + split) * SQL + q0 + l31] =
            make_float2(mrow, lrow);

    // ---- last block for (b,qblk) combines the splits ----
    __threadfence();   // release: partials visible device-wide before count
    if (tid == 0) {
        unsigned int old = atomicAdd(&cnt[b * NQBLK + qblk], 1u);
        red_flag = (old == (unsigned int)(nactive - 1));
    }
    __syncthreads();
    if (!red_flag) return;
    __threadfence();   // acquire: see all other blocks' partials

    // reduce 128 q rows x 64 d: thread -> (q = tid>>1, d-half = (tid&1)*32)
    const int q  = qblk * 128 + (tid >> 1);
    const int dh = (tid & 1) << 5;

    float m[NSPLIT], l[NSPLIT];
    float M = -1e30f;
    for (int s2 = 0; s2 < nactive; ++s2) {
        float2 ml = MLpart[((size_t)b * NSPLIT + s2) * SQL + q];
        m[s2] = ml.x; l[s2] = ml.y;
        M = fmaxf(M, ml.x);
    }
    float L = 0.f;
    float acc[32];
    #pragma unroll
    for (int i = 0; i < 32; ++i) acc[i] = 0.f;
    for (int s2 = 0; s2 < nactive; ++s2) {
        const float w = exp2f((m[s2] - M) * LOG2E);
        L += l[s2] * w;
        const unsigned short* p =
            Opart + (((size_t)b * NSPLIT + s2) * SQL + q) * DH + dh;
        #pragma unroll
        for (int i = 0; i < 4; ++i) {
            u16x8 a = *(const u16x8*)(p + i * 8);
            #pragma unroll
            for (int j = 0; j < 8; ++j) acc[i * 8 + j] += w * bf2f(a[j]);
        }
    }
    const float inv = 1.0f / L;
    float* outp = out + ((size_t)b * SQL + q) * DH + dh;
    #pragma unroll
    for (int i = 0; i < 8; ++i) {
        f32x4 ov;
        ov[0] = acc[i*4+0] * inv; ov[1] = acc[i*4+1] * inv;
        ov[2] = acc[i*4+2] * inv; ov[3] = acc[i*4+3] * inv;
        *(f32x4*)(outp + i * 4) = ov;
    }
}

extern "C" void kernel_launch(void* const* d_in, const int* in_sizes, int n_in,
                              void* d_out, int out_size, void* d_ws, size_t ws_size,
                              hipStream_t stream) {
    const float* Q  = (const float*)d_in[0];
    const float* K  = (const float*)d_in[1];
    const float* V  = (const float*)d_in[2];
    const int*   vl = (const int*)d_in[3];
    float* out = (float*)d_out;

    unsigned short* Qb = (unsigned short*)d_ws;                      // 4 MB
    unsigned short* Kb = Qb + (size_t)NB * SQL * DH;                 // 4 MB
    unsigned short* Vt = Kb + (size_t)NB * SKL * DH;                 // 4 MB
    unsigned short* Opart = Vt + (size_t)NB * SKL * DH;              // 33.5 MB bf16
    float2* MLpart = (float2*)(Opart + (size_t)NB * NSPLIT * SQL * DH); // 2 MB
    unsigned int* cnt = (unsigned int*)(MLpart + (size_t)NB * NSPLIT * SQL);

    (void)hipMemsetAsync(cnt, 0, NB * NQBLK * sizeof(unsigned int), stream);
    prep_kernel<<<dim3(2560), dim3(256), 0, stream>>>(Q, K, V, Qb, Kb, Vt);
    attn_kernel<<<dim3(NQBLK, NSPLIT, NB), dim3(256), 0, stream>>>(
        Qb, Kb, Vt, vl, Opart, MLpart, cnt, out);
}

// Round 6
// 111.141 us; speedup vs baseline: 2.7671x; 2.7671x over previous
//
#include <hip/hip_runtime.h>

#define NB 16
#define SQL 2048
#define SKL 2048
#define DH 64
#define NSPLIT 8
#define CHUNK 256          // keys per split = 4 tiles of 64

typedef __attribute__((ext_vector_type(8)))  short bf16x8;
typedef __attribute__((ext_vector_type(4)))  unsigned short u16x4;
typedef __attribute__((ext_vector_type(8)))  unsigned short u16x8;
typedef __attribute__((ext_vector_type(4)))  float f32x4;
typedef __attribute__((ext_vector_type(16))) float f32x16;

#define LOG2E 1.4426950408889634f
#define K1 (0.125f * LOG2E)   // 1/sqrt(64) folded into exp2 argument

__device__ __forceinline__ unsigned short f2bf(float f) {
    unsigned int u = __builtin_bit_cast(unsigned int, f);
    u += 0x7fffu + ((u >> 16) & 1u);
    return (unsigned short)(u >> 16);
}
__device__ __forceinline__ float bf2f(unsigned short h) {
    return __builtin_bit_cast(float, (unsigned int)h << 16);
}
__device__ __forceinline__ bf16x8 pack8(float4 a, float4 b) {
    u16x8 o;
    o[0] = f2bf(a.x); o[1] = f2bf(a.y); o[2] = f2bf(a.z); o[3] = f2bf(a.w);
    o[4] = f2bf(b.x); o[5] = f2bf(b.y); o[6] = f2bf(b.z); o[7] = f2bf(b.w);
    return __builtin_bit_cast(bf16x8, o);
}

// ---------------------------------------------------------------------------
// Prep: V fp32 -> V^T bf16 only (512 blocks). Q/K conversion folded into attn.
// ---------------------------------------------------------------------------
__global__ __launch_bounds__(256) void prep_kernel(
    const float* __restrict__ V, unsigned short* __restrict__ Vt) {
    const int t  = blockIdx.x;          // 0..511
    const int b  = t >> 5;              // batch
    const int kb = (t & 31) << 6;       // key base
    __shared__ float tile[64][65];
    const int tid = threadIdx.x;
    {
        const int r  = tid >> 2;
        const int cg = (tid & 3) << 4;
        const float* vsrc = V + ((size_t)b * SKL + (kb + r)) * DH;
        #pragma unroll
        for (int i = 0; i < 4; ++i) {
            float4 x = *(const float4*)(vsrc + cg + i * 4);
            tile[r][cg + i*4 + 0] = x.x;
            tile[r][cg + i*4 + 1] = x.y;
            tile[r][cg + i*4 + 2] = x.z;
            tile[r][cg + i*4 + 3] = x.w;
        }
    }
    __syncthreads();
    {
        const int d  = tid >> 2;
        const int kg = (tid & 3) << 4;
        unsigned short* dst = Vt + ((size_t)b * DH + d) * SKL + kb + kg;
        u16x8 o0, o1;
        #pragma unroll
        for (int j = 0; j < 8; ++j) o0[j] = f2bf(tile[kg + j][d]);
        #pragma unroll
        for (int j = 0; j < 8; ++j) o1[j] = f2bf(tile[kg + 8 + j][d]);
        *(u16x8*)(dst)     = o0;
        *(u16x8*)(dst + 8) = o1;
    }
}

// ---------------------------------------------------------------------------
// Flash attention, S^T/O^T form, 32x32x16 MFMA. Block = 4 waves, 128 q-rows
// (32/wave, q-col = lane&31). K-tile 64 keys. 16B-unit XOR-swizzled LDS.
// Reads Q,K fp32 directly (convert at staging); V^T bf16 from prep.
// ns==1 batches write normalized out directly; else bf16 partials to ws.
// NO cross-block fences/atomics (round-5 lesson: agent-scope fences thrash
// the non-coherent per-XCD L2s on gfx950 — 3x regression).
// ---------------------------------------------------------------------------
__global__ __launch_bounds__(256, 3) void attn_kernel(
    const float* __restrict__ Q,
    const float* __restrict__ K,
    const unsigned short* __restrict__ Vt,
    const int* __restrict__ valid_lens,
    unsigned short* __restrict__ Opart,
    float2* __restrict__ MLpart,
    float* __restrict__ out) {
    const int qblk  = blockIdx.x;
    const int split = blockIdx.y;
    const int b     = blockIdx.z;

    const int valid  = valid_lens[b];
    const int kstart = split * CHUNK;
    if (kstart >= valid) return;                 // empty split
    const int kend    = (valid < kstart + CHUNK) ? valid : (kstart + CHUNK);
    const int ntiles  = (kend - kstart + 63) >> 6;
    const int nactive = (valid + CHUNK - 1) / CHUNK;   // 1..NSPLIT

    const int tid  = threadIdx.x;
    const int wave = tid >> 6;
    const int lane = tid & 63;
    const int l31  = lane & 31;
    const int h2   = lane >> 5;
    const int sw   = l31 & 7;                    // swizzle key

    __shared__ unsigned short Klds[64][64];      // [key][d], unit^=(key&7)
    __shared__ unsigned short Vlds[64][64];      // [d][key], unit^=(d&7)
    __shared__ unsigned short Plds[4][32][64];   // per-wave [q][key], unit^=(q&7)

    // Q B-fragments from fp32: lane n=l31 (q), k = ks*16 + h2*8 + j
    const int q0 = qblk * 128 + wave * 32;
    const float* qptr = Q + ((size_t)b * SQL + q0 + l31) * DH + h2 * 8;
    bf16x8 qf[4];
    #pragma unroll
    for (int ks = 0; ks < 4; ++ks)
        qf[ks] = pack8(*(const float4*)(qptr + ks * 16),
                       *(const float4*)(qptr + ks * 16 + 4));

    const float* kbase = K + (size_t)b * SKL * DH;
    const unsigned short* vbase = Vt + (size_t)b * DH * SKL;

    f32x16 o[2];
    #pragma unroll
    for (int i = 0; i < 2; ++i)
        #pragma unroll
        for (int r = 0; r < 16; ++r) o[i][r] = 0.f;
    float mrow = -1e30f, lrow = 0.f;

    // staging registers (tile pipeline): K fp32, V^T bf16
    float4 kra[2], krb[2];
    u16x8  vreg[2];
    #pragma unroll
    for (int i = 0; i < 2; ++i) {
        const int c = i * 256 + tid, r = c >> 3, col = (c & 7) << 3;
        kra[i]  = *(const float4*)(kbase + (size_t)(kstart + r) * DH + col);
        krb[i]  = *(const float4*)(kbase + (size_t)(kstart + r) * DH + col + 4);
        vreg[i] = *(const u16x8*)(vbase + (size_t)r * SKL + kstart + col);
    }

    for (int kt = 0; kt < ntiles; ++kt) {
        const int kb = kstart + (kt << 6);
        __syncthreads();                         // prev tile's LDS reads done
        #pragma unroll
        for (int i = 0; i < 2; ++i) {
            const int c = i * 256 + tid, r = c >> 3;
            const int pc = ((c & 7) ^ (r & 7)) << 3;
            *(bf16x8*)&Klds[r][pc] = pack8(kra[i], krb[i]);
            *(u16x8*)&Vlds[r][pc]  = vreg[i];
        }
        __syncthreads();
        if (kt + 1 < ntiles) {                   // preload next tile -> regs
            const int kn = kb + 64;
            #pragma unroll
            for (int i = 0; i < 2; ++i) {
                const int c = i * 256 + tid, r = c >> 3, col = (c & 7) << 3;
                kra[i]  = *(const float4*)(kbase + (size_t)(kn + r) * DH + col);
                krb[i]  = *(const float4*)(kbase + (size_t)(kn + r) * DH + col + 4);
                vreg[i] = *(const u16x8*)(vbase + (size_t)r * SKL + kn + col);
            }
        }

        // ---- S^T = K . Q^T : 2 key-subtiles x 4 K-steps of 32x32x16 ----
        f32x16 s[2];
        #pragma unroll
        for (int t = 0; t < 2; ++t) {
            #pragma unroll
            for (int r = 0; r < 16; ++r) s[t][r] = 0.f;
            #pragma unroll
            for (int ks = 0; ks < 4; ++ks) {
                const bf16x8 kf = *(const bf16x8*)
                    &Klds[t * 32 + l31][((2 * ks + h2) ^ sw) << 3];
                s[t] = __builtin_amdgcn_mfma_f32_32x32x16_bf16(kf, qf[ks], s[t], 0, 0, 0);
            }
        }

        // ---- mask boundary tile; key(reg)=kb+t*32+(r&3)+8*(r>>2)+4*h2 ----
        if (kb + 64 > kend) {
            #pragma unroll
            for (int t = 0; t < 2; ++t)
                #pragma unroll
                for (int r = 0; r < 16; ++r)
                    if (kb + t * 32 + (r & 3) + 8 * (r >> 2) + 4 * h2 >= kend)
                        s[t][r] = -1e30f;
        }

        // ---- online softmax; q per-lane, rows split across lane^32 ----
        float tmax = -1e30f;
        #pragma unroll
        for (int t = 0; t < 2; ++t)
            #pragma unroll
            for (int r = 0; r < 16; ++r) tmax = fmaxf(tmax, s[t][r]);
        tmax = fmaxf(tmax, __shfl_xor(tmax, 32));

        const float mnew  = fmaxf(mrow, 0.125f * tmax);
        const float alpha = exp2f((mrow - mnew) * LOG2E);
        const float mk    = mnew * LOG2E;
        float rs = 0.f;
        #pragma unroll
        for (int t = 0; t < 2; ++t)
            #pragma unroll
            for (int r = 0; r < 16; ++r) {
                const float p = exp2f(fmaf(s[t][r], K1, -mk));
                s[t][r] = p;
                rs += p;
            }
        rs += __shfl_xor(rs, 32);
        lrow = lrow * alpha + rs;
        mrow = mnew;
        #pragma unroll
        for (int i = 0; i < 2; ++i)
            #pragma unroll
            for (int r = 0; r < 16; ++r) o[i][r] *= alpha;

        // ---- P -> LDS (bf16, swizzled): 8 writes of 4 contiguous keys ----
        #pragma unroll
        for (int t = 0; t < 2; ++t)
            #pragma unroll
            for (int g = 0; g < 4; ++g) {
                u16x4 pw;
                pw[0] = f2bf(s[t][g * 4 + 0]); pw[1] = f2bf(s[t][g * 4 + 1]);
                pw[2] = f2bf(s[t][g * 4 + 2]); pw[3] = f2bf(s[t][g * 4 + 3]);
                const int unit = (4 * t + g) ^ sw;
                *(u16x4*)&Plds[wave][l31][(unit << 3) + (h2 << 2)] = pw;
            }
        bf16x8 pf[4];
        #pragma unroll
        for (int ks = 0; ks < 4; ++ks)
            pf[ks] = *(const bf16x8*)&Plds[wave][l31][((2 * ks + h2) ^ sw) << 3];

        // ---- O^T += V^T . P^T : 2 d-subtiles x 4 K-steps ----
        #pragma unroll
        for (int dt = 0; dt < 2; ++dt)
            #pragma unroll
            for (int ks = 0; ks < 4; ++ks) {
                const bf16x8 vf = *(const bf16x8*)
                    &Vlds[dt * 32 + l31][((2 * ks + h2) ^ sw) << 3];
                o[dt] = __builtin_amdgcn_mfma_f32_32x32x16_bf16(vf, pf[ks], o[dt], 0, 0, 0);
            }
    }

    // ---- ns==1: write normalized output directly ----
    if (nactive == 1) {
        const float inv = 1.0f / lrow;
        float* op = out + ((size_t)b * SQL + q0 + l31) * DH;
        #pragma unroll
        for (int dt = 0; dt < 2; ++dt)
            #pragma unroll
            for (int g = 0; g < 4; ++g) {
                f32x4 ov;
                ov[0] = o[dt][g*4+0] * inv; ov[1] = o[dt][g*4+1] * inv;
                ov[2] = o[dt][g*4+2] * inv; ov[3] = o[dt][g*4+3] * inv;
                *(f32x4*)(op + dt * 32 + 8 * g + 4 * h2) = ov;
            }
        return;
    }

    // ---- partials: Opart[b][split][q][d] bf16; d = dt*32+8g+4h2+r ----
    unsigned short* op = Opart +
        (((size_t)b * NSPLIT + split) * SQL + q0 + l31) * DH;
    #pragma unroll
    for (int dt = 0; dt < 2; ++dt)
        #pragma unroll
        for (int g = 0; g < 4; ++g) {
            u16x4 ow;
            ow[0] = f2bf(o[dt][g * 4 + 0]); ow[1] = f2bf(o[dt][g * 4 + 1]);
            ow[2] = f2bf(o[dt][g * 4 + 2]); ow[3] = f2bf(o[dt][g * 4 + 3]);
            *(u16x4*)(op + dt * 32 + 8 * g + 4 * h2) = ow;
        }
    if (h2 == 0)
        MLpart[((size_t)b * NSPLIT + split) * SQL + q0 + l31] =
            make_float2(mrow, lrow);
}

// ---------------------------------------------------------------------------
// Combine partials (skips ns==1 batches — attn wrote those directly).
// ---------------------------------------------------------------------------
__global__ __launch_bounds__(256) void reduce_kernel(
    const unsigned short* __restrict__ Opart, const float2* __restrict__ MLpart,
    const int* __restrict__ valid_lens, float* __restrict__ out) {
    const int b   = blockIdx.y;
    const int ns  = (valid_lens[b] + CHUNK - 1) / CHUNK;   // 1..8
    if (ns == 1) return;
    const int tid = threadIdx.x;
    const int q   = blockIdx.x * 64 + (tid >> 2);
    const int dg  = (tid & 3) << 4;

    float m[NSPLIT], l[NSPLIT];
    float M = -1e30f;
    for (int s = 0; s < ns; ++s) {
        float2 ml = MLpart[((size_t)b * NSPLIT + s) * SQL + q];
        m[s] = ml.x; l[s] = ml.y;
        M = fmaxf(M, ml.x);
    }
    float L = 0.f;
    float acc[16];
    #pragma unroll
    for (int i = 0; i < 16; ++i) acc[i] = 0.f;
    for (int s = 0; s < ns; ++s) {
        const float w = exp2f((m[s] - M) * LOG2E);
        L += l[s] * w;
        const unsigned short* p =
            Opart + (((size_t)b * NSPLIT + s) * SQL + q) * DH + dg;
        u16x8 a0 = *(const u16x8*)(p);
        u16x8 a1 = *(const u16x8*)(p + 8);
        #pragma unroll
        for (int i = 0; i < 8; ++i) acc[i]     += w * bf2f(a0[i]);
        #pragma unroll
        for (int i = 0; i < 8; ++i) acc[8 + i] += w * bf2f(a1[i]);
    }
    const float inv = 1.0f / L;
    float* op = out + ((size_t)b * SQL + q) * DH + dg;
    f32x4 ov;
    #pragma unroll
    for (int i = 0; i < 4; ++i) {
        ov[0] = acc[i*4+0] * inv; ov[1] = acc[i*4+1] * inv;
        ov[2] = acc[i*4+2] * inv; ov[3] = acc[i*4+3] * inv;
        *(f32x4*)(op + i * 4) = ov;
    }
}

extern "C" void kernel_launch(void* const* d_in, const int* in_sizes, int n_in,
                              void* d_out, int out_size, void* d_ws, size_t ws_size,
                              hipStream_t stream) {
    const float* Q  = (const float*)d_in[0];
    const float* K  = (const float*)d_in[1];
    const float* V  = (const float*)d_in[2];
    const int*   vl = (const int*)d_in[3];
    float* out = (float*)d_out;

    unsigned short* Vt = (unsigned short*)d_ws;                      // 4 MB
    unsigned short* Opart = Vt + (size_t)NB * SKL * DH;              // 33.5 MB bf16
    float2* MLpart = (float2*)(Opart + (size_t)NB * NSPLIT * SQL * DH); // 2 MB

    prep_kernel<<<dim3(512), dim3(256), 0, stream>>>(V, Vt);
    attn_kernel<<<dim3(SQL / 128, NSPLIT, NB), dim3(256), 0, stream>>>(
        Q, K, Vt, vl, Opart, MLpart, out);
    reduce_kernel<<<dim3(SQL / 64, NB), dim3(256), 0, stream>>>(
        Opart, MLpart, vl, out);
}